// Round 9
// baseline (1690.109 us; speedup 1.0000x reference)
//
#include <hip/hip_runtime.h>

typedef _Float16 f16;
typedef _Float16 f16x8 __attribute__((ext_vector_type(8)));
typedef float f32x4 __attribute__((ext_vector_type(4)));

#define N_ROWS 500000
#define EPS_LOG 1e-7f
#define EPS_LN  1e-5f

// ws layout (819200 bytes total, footprint proven safe):
//   f16 idx [0, 10240)      : W1p [256][40], W1p[j][k]=W1[j][k] (k<39), k=39 -> 0
//   bytes [20480, 32768)    : f32 cst block:
//       cst[0..256)   = w8g[j] = W8[j]*gamma[j]
//       cst[256]      = s8  = sum_j w8g[j]
//       cst[257]      = cb8 = beta@W8^T + b8
//       cst[1536+li*256+j] = bb[li][j] = beta@W^T + b   (li=0..5 -> layers 2..7)
//   f16 idx [16384, 409600) : Wg layers 2..7 SLAB-PERMUTED:
//       idx = 16384 + li*65536 + kt*8192 + kgrp*2048 + j*8 + e
//       value = W[j][k]*gamma[k],  k = kt*32 + kgrp*8 + e
#define CST_BYTE_OFF 20480

// ---------------- prep (unchanged from r8, proven) ----------------
__global__ void prep_kernel(const float* __restrict__ W1,
                            const float* __restrict__ W2, const float* __restrict__ W3,
                            const float* __restrict__ W4, const float* __restrict__ W5,
                            const float* __restrict__ W6, const float* __restrict__ W7,
                            const float* __restrict__ W8, const float* __restrict__ b8,
                            const float* __restrict__ b2, const float* __restrict__ b3,
                            const float* __restrict__ b4, const float* __restrict__ b5,
                            const float* __restrict__ b6, const float* __restrict__ b7,
                            const float* __restrict__ gamma, const float* __restrict__ beta,
                            f16* __restrict__ ws) {
  float* cstF = (float*)((char*)ws + CST_BYTE_OFF);
  int idx = blockIdx.x * 256 + threadIdx.x;
  if (idx < 10240) {            // W1p [256][40]
    int j = idx / 40, k = idx - j * 40;
    ws[idx] = (f16)((k < 39) ? W1[j * 39 + k] : 0.0f);
  } else if (idx < 16384) {
    // cst region lives at bytes [20480,32768) — written below
  } else if (idx < 409600) {    // Wg = W*gamma, slab-permuted for LDS staging
    int o = idx - 16384;
    int li = o >> 16;  o &= 65535;
    const float* W = (li == 0) ? W2 : (li == 1) ? W3 : (li == 2) ? W4
                   : (li == 3) ? W5 : (li == 4) ? W6 : W7;
    int e = o & 7, j = (o >> 3) & 255, kgrp = (o >> 11) & 3, kt = o >> 13;
    int k = kt * 32 + kgrp * 8 + e;
    ws[idx] = (f16)(W[j * 256 + k] * gamma[k]);
  } else if (idx < 411136) {    // bb[li][j] = beta@W^T + b
    int o = idx - 409600;
    int li = o >> 8, j = o & 255;
    const float* W = (li == 0) ? W2 : (li == 1) ? W3 : (li == 2) ? W4
                   : (li == 3) ? W5 : (li == 4) ? W6 : W7;
    const float* b = (li == 0) ? b2 : (li == 1) ? b3 : (li == 2) ? b4
                   : (li == 3) ? b5 : (li == 4) ? b6 : b7;
    float bb = 0.f;
    for (int k = 0; k < 256; ++k) bb = fmaf(W[j * 256 + k], beta[k], bb);
    cstF[1536 + li * 256 + j] = bb + b[j];
  } else if (idx < 411392) {    // w8g
    int j = idx - 411136;
    cstF[j] = W8[j] * gamma[j];
  } else if (idx == 411392) {   // s8, cb8
    float s8 = 0.f, cb = 0.f;
    for (int k = 0; k < 256; ++k) {
      float w = W8[k];
      s8 = fmaf(w, gamma[k], s8);
      cb = fmaf(w, beta[k], cb);
    }
    cstF[256] = s8;
    cstF[257] = cb + b8[0];
  }
}

// ---------------- fused MLP (r7 structure + reg-pressure fixes) ----------------
// 256 threads = 4 waves; 128 rows/block; wave owns rows [wid*32, wid*32+32).
// All hbuf traffic wave-private at row-stride 256 (r5-proven race-free).
// Slab staged global->VGPR->ds_write (r6: global_load_lds miscompiles here).
// Reg discipline: waves_per_eu(2,2) (LDS caps at 2 blocks/CU anyway; r7's
// 4-wave reg target caused 169 MB scratch spill), staging pairs loadA (hidden
// under compute) / loadB (post-compute), nothing staged across epilogues.
__global__ __launch_bounds__(256)
__attribute__((amdgpu_waves_per_eu(2, 2)))
void mlp_kernel(const float* __restrict__ x, const f16* __restrict__ wsw,
                const float* __restrict__ b1, float* __restrict__ out) {
  __shared__ __attribute__((aligned(16))) f16 hbuf[128 * 256];   // 64 KB
  __shared__ __attribute__((aligned(16))) f16 wslab[8192];       // 16 KB

  const float* cstF = (const float*)((const char*)wsw + CST_BYTE_OFF);
  const int t = threadIdx.x;
  const int lane = t & 63;
  const int wid = t >> 6;
  const int lm = lane & 15;
  const int lg = lane >> 4;
  const long rowbase = (long)blockIdx.x * 128;
  const int R0 = wid * 32;
  const int myrow0 = R0 + lm;
  const int myrow1 = R0 + 16 + lm;
  const int sA0 = ((myrow0 >> 1) & 7) << 3;
  const int sA1 = ((myrow1 >> 1) & 7) << 3;

  // staging pairs (named regs; short liveness by construction)
  f16x8 la0, la1, lb0, lb1;
  auto loadA = [&](const f16* g) {
    la0 = *(const f16x8*)(g + t * 8);
    la1 = *(const f16x8*)(g + (256 + t) * 8);
  };
  auto loadB = [&](const f16* g) {
    lb0 = *(const f16x8*)(g + (512 + t) * 8);
    lb1 = *(const f16x8*)(g + (768 + t) * 8);
  };
  auto writeAB = [&]() {
    *(f16x8*)&wslab[t * 8] = la0;
    *(f16x8*)&wslab[(256 + t) * 8] = la1;
    *(f16x8*)&wslab[(512 + t) * 8] = lb0;
    *(f16x8*)&wslab[(768 + t) * 8] = lb1;
  };

  // ---- input fill (wave-private, stride 256, swizzled, zero-padded) ----
  #pragma unroll 1
  for (int i = 0; i < 32; ++i) {
    int r = R0 + i;
    long gr = rowbase + r;
    float tv = 0.0f;
    if (lane < 39) {
      float xv = (gr < N_ROWS) ? x[gr * 39 + lane] : 1.0f;
      tv = 0.1f * __logf(xv + EPS_LOG);
    }
    hbuf[r * 256 + (lane ^ (((r >> 1) & 7) << 3))] = (f16)tv;
  }

  f32x4 acc0[16], acc1[16];

  auto compute = [&](int kt) {
    f16x8 av0 = *(const f16x8*)&hbuf[myrow0 * 256 + ((kt * 32 + lg * 8) ^ sA0)];
    f16x8 av1 = *(const f16x8*)&hbuf[myrow1 * 256 + ((kt * 32 + lg * 8) ^ sA1)];
    #pragma unroll
    for (int nt = 0; nt < 16; ++nt) {
      f16x8 bf = *(const f16x8*)&wslab[lg * 2048 + (nt * 16 + lm) * 8];
      acc0[nt] = __builtin_amdgcn_mfma_f32_16x16x32_f16(av0, bf, acc0[nt], 0, 0, 0);
      acc1[nt] = __builtin_amdgcn_mfma_f32_16x16x32_f16(av1, bf, acc1[nt], 0, 0, 0);
    }
  };

  // epilogue, one 16-row tile (r7-proven): lane (lg,lm) holds acc[nt][i] =
  // row rbase+lg*4+i, col nt*16+lm. Store z=(a-mu)*is (wave-private rows).
  auto do_tile = [&](f32x4* acc, int rbase, bool tanh_act, const float* cvec) {
    float nm[4] = {0, 0, 0, 0}, nq[4] = {0, 0, 0, 0};
    #pragma unroll
    for (int nt = 0; nt < 16; ++nt) {
      float c0 = cvec[nt * 16 + lm];
      #pragma unroll
      for (int i = 0; i < 4; ++i) {
        float v = acc[nt][i] + c0;
        float a;
        if (tanh_act) {
          float e2 = __expf(2.f * v);
          a = 1.f - 2.f / (e2 + 1.f);
        } else {
          a = (v > 0.f) ? v : (__expf(v) - 1.f);
        }
        acc[nt][i] = a;
        nm[i] += a;
        nq[i] = fmaf(a, a, nq[i]);
      }
    }
    #pragma unroll
    for (int off = 1; off < 16; off <<= 1) {
      #pragma unroll
      for (int i = 0; i < 4; ++i) {
        nm[i] += __shfl_xor(nm[i], off, 64);
        nq[i] += __shfl_xor(nq[i], off, 64);
      }
    }
    float mu[4], is_[4];
    #pragma unroll
    for (int i = 0; i < 4; ++i) {
      float m = nm[i] * (1.f / 256.f);
      float var = nq[i] * (1.f / 256.f) - m * m;
      mu[i] = m;
      is_[i] = rsqrtf(var + EPS_LN);
    }
    #pragma unroll
    for (int nt = 0; nt < 16; ++nt) {
      int col = nt * 16 + lm;
      #pragma unroll
      for (int i = 0; i < 4; ++i) {
        int r = rbase + lg * 4 + i;
        hbuf[r * 256 + (col ^ (((r >> 1) & 7) << 3))] =
            (f16)((acc[nt][i] - mu[i]) * is_[i]);
      }
    }
  };

  // layer-7 epilogue fused with layer 8: out[row] = is*(dot - mu*s8) + cb8
  auto final_tile = [&](f32x4* acc, int rbase) {
    const float* bb7 = cstF + 1536 + 5 * 256;
    float s8 = cstF[256], cb8 = cstF[257];
    float nm[4] = {0, 0, 0, 0}, nq[4] = {0, 0, 0, 0}, dt[4] = {0, 0, 0, 0};
    #pragma unroll
    for (int nt = 0; nt < 16; ++nt) {
      float c0 = bb7[nt * 16 + lm];
      float w8 = cstF[nt * 16 + lm];
      #pragma unroll
      for (int i = 0; i < 4; ++i) {
        float v = acc[nt][i] + c0;
        float a = (v > 0.f) ? v : (__expf(v) - 1.f);
        nm[i] += a;
        nq[i] = fmaf(a, a, nq[i]);
        dt[i] = fmaf(a, w8, dt[i]);
      }
    }
    #pragma unroll
    for (int off = 1; off < 16; off <<= 1) {
      #pragma unroll
      for (int i = 0; i < 4; ++i) {
        nm[i] += __shfl_xor(nm[i], off, 64);
        nq[i] += __shfl_xor(nq[i], off, 64);
        dt[i] += __shfl_xor(dt[i], off, 64);
      }
    }
    if (lm == 0) {
      #pragma unroll
      for (int i = 0; i < 4; ++i) {
        float mu = nm[i] * (1.f / 256.f);
        float is = rsqrtf(nq[i] * (1.f / 256.f) - mu * mu + EPS_LN);
        long gr = rowbase + rbase + lg * 4 + i;
        if (gr < N_ROWS) out[gr] = fmaf(is, dt[i] - mu * s8, cb8);
      }
    }
  };

  // ================= layer 1: z1 = LN-norm(tanh(t @ W1^T + b1)), K=64 =============
  {
    #pragma unroll
    for (int i = 0; i < 16; ++i) { acc0[i] = (f32x4){0,0,0,0}; acc1[i] = (f32x4){0,0,0,0}; }
    #pragma unroll
    for (int kt = 0; kt < 2; ++kt) {
      f16x8 av0 = *(const f16x8*)&hbuf[myrow0 * 256 + ((kt * 32 + lg * 8) ^ sA0)];
      f16x8 av1 = *(const f16x8*)&hbuf[myrow1 * 256 + ((kt * 32 + lg * 8) ^ sA1)];
      #pragma unroll
      for (int nt = 0; nt < 16; ++nt) {
        int j40 = (nt * 16 + lm) * 40;
        f16x8 bf = 0;
        if (kt == 0)       bf = *(const f16x8*)&wsw[j40 + lg * 8];
        else if (lg == 0)  bf = *(const f16x8*)&wsw[j40 + 32];
        acc0[nt] = __builtin_amdgcn_mfma_f32_16x16x32_f16(av0, bf, acc0[nt], 0, 0, 0);
        acc1[nt] = __builtin_amdgcn_mfma_f32_16x16x32_f16(av1, bf, acc1[nt], 0, 0, 0);
      }
    }
    do_tile(acc0, R0,      true, b1);
    do_tile(acc1, R0 + 16, true, b1);
  }

  // ================= layers 2..7 =================
  const f16* WgBase = wsw + 16384;
  #pragma unroll 1
  for (int li = 0; li < 6; ++li) {
    const f16* Wb = WgBase + li * 65536;
    // layer-top stage of slab 0 (exposed ~one L2 latency; other block hides it)
    loadA(Wb);
    loadB(Wb);
    writeAB();
    #pragma unroll
    for (int i = 0; i < 16; ++i) { acc0[i] = (f32x4){0,0,0,0}; acc1[i] = (f32x4){0,0,0,0}; }
    #pragma unroll 1
    for (int kt = 0; kt < 8; ++kt) {
      __syncthreads();                 // READY: slab kt visible (lgkm drained)
      if (kt < 7) loadA(Wb + (kt + 1) * 8192);   // hidden under compute
      compute(kt);
      if (kt < 7) loadB(Wb + (kt + 1) * 8192);
      __syncthreads();                 // FREE: all waves done reading slab kt
      if (kt < 7) writeAB();
    }
    if (li < 5) {
      do_tile(acc0, R0,      false, cstF + 1536 + li * 256);
      do_tile(acc1, R0 + 16, false, cstF + 1536 + li * 256);
    } else {
      final_tile(acc0, R0);
      final_tile(acc1, R0 + 16);
    }
  }
}

extern "C" void kernel_launch(void* const* d_in, const int* in_sizes, int n_in,
                              void* d_out, int out_size, void* d_ws, size_t ws_size,
                              hipStream_t stream) {
  const float* x  = (const float*)d_in[0];
  const float* W1 = (const float*)d_in[1];
  const float* b1 = (const float*)d_in[2];
  const float* W2 = (const float*)d_in[3];
  const float* b2 = (const float*)d_in[4];
  const float* W3 = (const float*)d_in[5];
  const float* b3 = (const float*)d_in[6];
  const float* W4 = (const float*)d_in[7];
  const float* b4 = (const float*)d_in[8];
  const float* W5 = (const float*)d_in[9];
  const float* b5 = (const float*)d_in[10];
  const float* W6 = (const float*)d_in[11];
  const float* b6 = (const float*)d_in[12];
  const float* W7 = (const float*)d_in[13];
  const float* b7 = (const float*)d_in[14];
  const float* W8 = (const float*)d_in[15];
  const float* b8 = (const float*)d_in[16];
  const float* gm = (const float*)d_in[17];
  const float* bt = (const float*)d_in[18];
  f16* ws = (f16*)d_ws;
  float* out = (float*)d_out;

  prep_kernel<<<1608, 256, 0, stream>>>(W1, W2, W3, W4, W5, W6, W7, W8, b8,
                                        b2, b3, b4, b5, b6, b7, gm, bt, ws);

  int nblk = (N_ROWS + 127) / 128;   // 3907
  mlp_kernel<<<nblk, 256, 0, stream>>>(x, ws, b1, out);
}